// Round 13
// baseline (180.276 us; speedup 1.0000x reference)
//
#include <hip/hip_runtime.h>

// ---------- types / helpers ----------
using bf8v = __bf16 __attribute__((ext_vector_type(8)));
using s4v  = short  __attribute__((ext_vector_type(4)));
using f4v  = float  __attribute__((ext_vector_type(4)));

#define L2E 1.44269504088896340f

__device__ __forceinline__ float ex2(float x){ float r; asm("v_exp_f32 %0, %1" : "=v"(r) : "v"(x)); return r; }
__device__ __forceinline__ float rcp_(float x){ float r; asm("v_rcp_f32 %0, %1" : "=v"(r) : "v"(x)); return r; }
__device__ __forceinline__ float sigm(float x){ return rcp_(1.0f + ex2(-L2E*x)); }
__device__ __forceinline__ float tanh_(float x){ return 1.0f - 2.0f*rcp_(1.0f + ex2(2.0f*L2E*x)); }
__device__ __forceinline__ short f2bf(float x){ return __builtin_bit_cast(short, (__bf16)x); }
__device__ __forceinline__ f4v splat4(float v){ f4v r = {v,v,v,v}; return r; }
__device__ __forceinline__ f4v mfma16(bf8v a, bf8v b, f4v c){
  return __builtin_amdgcn_mfma_f32_16x16x32_bf16(a, b, c, 0, 0, 0);
}
// paired reciprocal: {1/(1+e0), 1/(1+e1)} with ONE v_rcp per pair (saves 1 trans, +3 muls).
// No clamp: args bounded (gate |x|<~14 -> e<2^20, pair<2^40; silu |v|<~25 -> pair<2^72) << f32 max.
__device__ __forceinline__ float2 brcp2(float e0, float e1){
  float d0 = e0 + 1.0f, d1 = e1 + 1.0f;
  float inv = rcp_(d0*d1);
  return make_float2(d1*inv, d0*inv);
}

// ---------- prep: fragment-ize weights, fold W2/b2, x fragments, rowbias tail ----------
__global__ void prep_kernel(
    const float* __restrict__ x,
    const float* __restrict__ W_emb, const float* __restrict__ b_emb,
    const float* __restrict__ W_ih,  const float* __restrict__ W_hh,
    const float* __restrict__ b_ih,
    const float* __restrict__ Wg1,   const float* __restrict__ Wn1,
    const float* __restrict__ Wn2,
    const float* __restrict__ bg1,   const float* __restrict__ bn1,
    short* __restrict__ bhhf, short* __restrict__ wcxf, short* __restrict__ wchf,
    short* __restrict__ wn2f, short* __restrict__ w2f, float* __restrict__ b2,
    short* __restrict__ xfrag, short* __restrict__ xf2, float* __restrict__ rbf)
{
  __shared__ float pe_s[134];
  // ---- rb tail blocks: one block per t, rowbias in fragment layout ----
  if (blockIdx.x >= 2514){
    const int t = blockIdx.x - 2514;   // 0..63
    const int n = threadIdx.x;         // 0..255
    if (n < 134){
      float fr = expf(-(float)(n & ~1) * 9.210340371976184f / 134.f);
      float a = (float)t * fr;
      pe_s[n] = (n & 1) ? cosf(a) : sinf(a);
    }
    __syncthreads();
    float s = (n < 128) ? bg1[n] : bn1[n-128];
    const float* W = (n < 128) ? (Wg1 + n) : (Wn1 + (n-128));
    for (int k = 0; k < 134; ++k) s += pe_s[k] * W[(size_t)k*128];
    int mt = t>>4, lh = (t>>2)&3, r = t&3, nt = n>>4, l15 = n&15;
    rbf[(((nt*4 + mt)*64) + lh*16 + l15)*4 + r] = s;
    return;
  }

  int i = blockIdx.x*256 + threadIdx.x;
  if (i < 49152){ // W_hh fragments [kb4][nt24][lane][8]; B[k][n] = W_hh[n][k]
    int e = i&7, lane=(i>>3)&63, r=i>>9; int nt=r%24, kb=r/24;
    int k = kb*32 + ((lane>>4)<<3) + e;
    int n = nt*16 + (lane&15);
    bhhf[i] = f2bf(W_hh[n*128 + k]);
    return;
  }
  i -= 49152;
  if (i < 8192){ // Wcx B-fragments [nt16][lane][8]: rows k<6 of [Wg1|Wn1]; k>=6 zero (slot6 = seqvec at runtime)
    int e=i&7, lane=(i>>3)&63, nt=i>>9;
    int k = ((lane>>4)<<3) + e; int n = nt*16 + (lane&15);
    float v = 0.f;
    if (k < 6) v = (n < 128) ? Wg1[k*128 + n] : Wn1[k*128 + (n-128)];
    wcxf[i] = f2bf(v);
    return;
  }
  i -= 8192;
  if (i < 32768){ // Wch B-fragments [kb4][nt16][lane][8]: rows 6..133 of [Wg1|Wn1] (K=128 exact)
    int e=i&7, lane=(i>>3)&63, r=i>>9; int nt=r&15, kb=r>>4;
    int k = 6 + kb*32 + ((lane>>4)<<3) + e; int n = nt*16 + (lane&15);
    float v = (n < 128) ? Wg1[k*128 + n] : Wn1[k*128 + (n-128)];
    wchf[i] = f2bf(v);
    return;
  }
  i -= 32768;
  if (i < 16384){ // Wn2 B-fragments [kb4][nt8][lane][8]
    int e=i&7, lane=(i>>3)&63, r=i>>9; int nt=r%8, kb=r/8;
    int k = kb*32 + ((lane>>4)<<3) + e; int n = nt*16 + (lane&15);
    wn2f[i] = f2bf(Wn2[k*128 + n]);
    return;
  }
  i -= 16384;
  if (i < 12288){ // W2 = W_emb @ W_ih^T B-fragments [nt24][lane][8], K=32 (rows>=6 zero)
    int e=i&7, lane=(i>>3)&63, nt=i>>9;
    int k = ((lane>>4)<<3) + e; int n = nt*16 + (lane&15);
    float v = 0.f;
    if (k < 6){
      const float* we = W_emb + k*128; const float* wi = W_ih + n*128;
      float s = 0.f;
      for (int h2=0; h2<128; ++h2) s += we[h2]*wi[h2];
      v = s;
    }
    w2f[i] = f2bf(v);
    return;
  }
  i -= 12288;
  if (i < 384){ // b2 = b_ih + b_emb @ W_ih^T
    float s = b_ih[i]; const float* wi = W_ih + i*128;
    for (int h2=0; h2<128; ++h2) s += b_emb[h2]*wi[h2];
    b2[i] = s;
    return;
  }
  i -= 384;
  if (i < 524288){ // x fragments, lane = t for coalesced reads
    int t = i & 63, r = (i>>6)&15, grp = i>>10;
    const float* xr = x + ((size_t)(grp*16 + r)*64 + t)*6;
    s4v lo, hi;
    lo[0]=f2bf(xr[0]); lo[1]=f2bf(xr[1]); lo[2]=f2bf(xr[2]); lo[3]=f2bf(xr[3]);
    hi[0]=f2bf(xr[4]); hi[1]=f2bf(xr[5]); hi[2]=f2bf(1.0f); hi[3]=0;
    // gru layout: xfrag[grp][t][r][8]
    size_t o1 = ((size_t)(grp*64 + t)*16 + r)*8;
    *reinterpret_cast<s4v*>(xfrag + o1)     = lo;
    *reinterpret_cast<s4v*>(xfrag + o1 + 4) = hi;
    // feats layout: xf2[seq][t][8]
    size_t o2 = ((size_t)(grp*16 + r)*64 + t)*8;
    *reinterpret_cast<s4v*>(xf2 + o2)     = lo;
    *reinterpret_cast<s4v*>(xf2 + o2 + 4) = hi;
    return;
  }
}

// ---------- GRU: 16 seqs/block, 1 stream; 8 waves; 512 blocks (2/CU -> 4 waves/SIMD) ----------
// Trans-issue-bound: brcp2 pairs cut trans 24->18 per thread-step (low-latency form of R10's idea).
__global__ __launch_bounds__(512, 4) void gru_kernel(
    const short* __restrict__ xfrag,   // [512][64][16][8]
    const short* __restrict__ bhhf,    // [4][24][64][8]
    const short* __restrict__ w2f,     // [24][64][8]
    const float* __restrict__ b2,      // 384
    const float* __restrict__ b_hh,    // 384
    const short* __restrict__ wchf,    // [4][16][64][8]
    short* __restrict__ svb)           // (8192,256) bf16
{
  __shared__ alignas(16) short h_lds[2][16*128];  // [dbuf], XOR-swizzled rows
  const int tid = threadIdx.x;
  const int w = tid >> 6;
  const int lane = tid & 63;
  const int l15 = lane & 15, lhi = lane >> 4;
  const int blk = blockIdx.x;

  for (int i = tid; i < 16*128; i += 512) h_lds[0][i] = 0;

  // hoisted B fragments + biases
  bf8v bhh[4][3]; bf8v w2v[3];
  float b2v[3], bhv[3];
  #pragma unroll
  for (int g = 0; g < 3; ++g){
    int nt = g*8 + w;
    w2v[g] = *reinterpret_cast<const bf8v*>(w2f + ((nt*64 + lane)<<3));
    #pragma unroll
    for (int kb = 0; kb < 4; ++kb)
      bhh[kb][g] = *reinterpret_cast<const bf8v*>(bhhf + (((kb*24 + nt)*64 + lane)<<3));
    int col = nt*16 + l15;
    b2v[g] = b2[col]; bhv[g] = b_hh[col];
  }
  float hr0[4] = {0.f,0.f,0.f,0.f};
  __syncthreads();

  const short* xf0 = xfrag + (size_t)blk*8192 + l15*8;
  const int sw_r = (l15 & 7) << 4;

  bf8v ax0 = *reinterpret_cast<const bf8v*>(xf0);

#define GSTEP(P, T)                                                           \
  {                                                                           \
    int tn = (T) + 1; if (tn > 63) tn = 63;                                   \
    bf8v axn0 = *reinterpret_cast<const bf8v*>(xf0 + tn*128);                 \
    bf8v ah0[4];                                                              \
    _Pragma("unroll")                                                         \
    for (int kb = 0; kb < 4; ++kb){                                           \
      int off = l15*256 + ((kb*64 + lhi*16) ^ sw_r);                          \
      ah0[kb] = *reinterpret_cast<const bf8v*>((const char*)h_lds[P] + off);  \
    }                                                                         \
    f4v xg0[3], gh0[3];                                                       \
    _Pragma("unroll")                                                         \
    for (int g = 0; g < 3; ++g){                                              \
      xg0[g] = splat4(b2v[g]); xg0[g] = mfma16(ax0, w2v[g], xg0[g]);          \
      gh0[g] = splat4(bhv[g]);                                                \
      _Pragma("unroll")                                                       \
      for (int kb = 0; kb < 4; ++kb)                                          \
        gh0[g] = mfma16(ah0[kb], bhh[kb][g], gh0[g]);                         \
    }                                                                         \
    f4v er, ez;                                                               \
    _Pragma("unroll")                                                         \
    for (int r = 0; r < 4; ++r){                                              \
      er[r] = ex2(-L2E*(xg0[0][r] + gh0[0][r]));                              \
      ez[r] = ex2(-L2E*(xg0[1][r] + gh0[1][r]));                              \
    }                                                                         \
    float2 p0, p1;                                                            \
    f4v rg, zg;                                                               \
    p0 = brcp2(er[0], er[1]); rg[0] = p0.x; rg[1] = p0.y;                     \
    p1 = brcp2(er[2], er[3]); rg[2] = p1.x; rg[3] = p1.y;                     \
    p0 = brcp2(ez[0], ez[1]); zg[0] = p0.x; zg[1] = p0.y;                     \
    p1 = brcp2(ez[2], ez[3]); zg[2] = p1.x; zg[3] = p1.y;                     \
    f4v en;                                                                   \
    _Pragma("unroll")                                                         \
    for (int r = 0; r < 4; ++r)                                               \
      en[r] = ex2(2.0f*L2E*(xg0[2][r] + rg[r]*gh0[2][r]));                    \
    f4v in_;                                                                  \
    p0 = brcp2(en[0], en[1]); in_[0] = p0.x; in_[1] = p0.y;                   \
    p1 = brcp2(en[2], en[3]); in_[2] = p1.x; in_[3] = p1.y;                   \
    _Pragma("unroll")                                                         \
    for (int r = 0; r < 4; ++r){                                              \
      int s = lhi*4 + r;                                                      \
      int woff = s*256 + (((w*16 + l15)*2) ^ ((s&7)<<4));                     \
      float ng = 1.0f - 2.0f*in_[r];                                          \
      float hv = ng + zg[r]*(hr0[r] - ng); hr0[r] = hv;                       \
      *(short*)((char*)h_lds[P^1] + woff) = f2bf(hv);                         \
    }                                                                         \
    ax0 = axn0;                                                               \
    __syncthreads();                                                          \
  }

  for (int tt = 0; tt < 32; ++tt){
    GSTEP(0, 2*tt);
    GSTEP(1, 2*tt + 1);
  }
#undef GSTEP

  // ---- seqvec epilogue (PROVEN orientation): A = h frag (rows=seq), B = Wch frag (cols=n).
  {
    bf8v ah[4];
    #pragma unroll
    for (int kb = 0; kb < 4; ++kb){
      int off = l15*256 + ((kb*64 + lhi*16) ^ sw_r);
      ah[kb] = *reinterpret_cast<const bf8v*>((const char*)h_lds[0] + off);
    }
    #pragma unroll
    for (int j = 0; j < 2; ++j){
      int nt = w*2 + j;
      f4v a = {0.f,0.f,0.f,0.f};
      #pragma unroll
      for (int kb = 0; kb < 4; ++kb){
        bf8v wf = *reinterpret_cast<const bf8v*>(wchf + (((kb*16 + nt)*64 + lane)<<3));
        a = mfma16(ah[kb], wf, a);
      }
      #pragma unroll
      for (int r = 0; r < 4; ++r){
        int sq = blk*16 + lhi*4 + r;
        svb[(size_t)sq*256 + nt*16 + l15] = f2bf(a[r]);
      }
    }
  }
}

// ---------- feats: K=32 GEMM1 (x + seqvec slot) + rbf C-init, PROVEN orientation ----------
// launch_bounds(256,6); silu uses brcp2 pairs (rcp count halved).
__global__ __launch_bounds__(256, 6) void feats_kernel(
    const short* __restrict__ xf2, const short* __restrict__ svb,
    const float* __restrict__ rbf,
    const short* __restrict__ wcxf, const short* __restrict__ wn2f,
    const float* __restrict__ Wg2, const float* __restrict__ bg2,
    const float* __restrict__ bn2,
    float* __restrict__ partials)  // [8192][130] = {max, sumE, sumEV[128]}
{
  __shared__ alignas(16) short A2[64*128];  // silu val-hidden, bf16, XOR-swizzled (16KB)
  __shared__ float gp[2][64];
  __shared__ float gate_arr[64];

  const int tid = threadIdx.x;
  const int w = tid >> 6;
  const int lane = tid & 63;
  const int l15 = lane & 15, lhi = lane >> 4;
  const int seq = blockIdx.x;
  const int ntb = w*4;

  // x A-fragments (rows = t); only lhi==0 lanes carry data (k = 0..7)
  bf8v bx[4];
  #pragma unroll
  for (int mt=0;mt<4;++mt){
    bf8v z;
    #pragma unroll
    for (int e=0;e<8;++e) z[e] = (__bf16)0.f;
    bx[mt] = z;
  }
  if (lhi == 0){
    const short* xp = xf2 + (size_t)seq*512;
    #pragma unroll
    for (int mt=0;mt<4;++mt)
      bx[mt] = *reinterpret_cast<const bf8v*>(xp + (mt*16 + l15)*8);
  }

  float gd[4][4];
  #pragma unroll
  for (int mt=0;mt<4;++mt)
    #pragma unroll
    for (int r=0;r<4;++r) gd[mt][r] = 0.f;

  #pragma unroll
  for (int i = 0; i < 4; ++i){
    const int n16 = (ntb+i)*16;
    bf8v wb = *reinterpret_cast<const bf8v*>(wcxf + (((ntb+i)*64 + lane)<<3));
    if (lhi == 0)
      wb[6] = __builtin_bit_cast(__bf16, svb[(size_t)seq*256 + n16 + l15]);
    f4v acc[4];
    #pragma unroll
    for (int mt=0;mt<4;++mt){
      acc[mt] = *reinterpret_cast<const f4v*>(rbf + (((ntb+i)*4 + mt)*64 + lane)*4);
      acc[mt] = mfma16(bx[mt], wb, acc[mt]);
    }
    // acc[mt][r]: hidden[m = mt*16 + lhi*4 + r][n = n16 + l15]
    if (w < 2){
      float wg2s = Wg2[n16 + l15];
      #pragma unroll
      for (int mt=0;mt<4;++mt){
        f4v e, o;
        #pragma unroll
        for (int r=0;r<4;++r) e[r] = ex2(-L2E*acc[mt][r]);
        float2 q0 = brcp2(e[0], e[1]); o[0] = q0.x; o[1] = q0.y;
        float2 q1 = brcp2(e[2], e[3]); o[2] = q1.x; o[3] = q1.y;
        #pragma unroll
        for (int r=0;r<4;++r) gd[mt][r] += acc[mt][r]*o[r]*wg2s;
      }
    } else {
      #pragma unroll
      for (int mt=0;mt<4;++mt){
        f4v e, o;
        #pragma unroll
        for (int r=0;r<4;++r) e[r] = ex2(-L2E*acc[mt][r]);
        float2 q0 = brcp2(e[0], e[1]); o[0] = q0.x; o[1] = q0.y;
        float2 q1 = brcp2(e[2], e[3]); o[2] = q1.x; o[3] = q1.y;
        #pragma unroll
        for (int r=0;r<4;++r){
          float s = acc[mt][r]*o[r];
          int row = mt*16 + lhi*4 + r;
          int colb = (((w-2)*4 + i)*16 + l15)*2;
          int off = row*256 + (colb ^ ((row&7)<<4));
          *(short*)((char*)A2 + off) = f2bf(s);
        }
      }
    }
  }
  if (w < 2){
    #pragma unroll
    for (int mt=0;mt<4;++mt)
      #pragma unroll
      for (int r=0;r<4;++r){
        float p = gd[mt][r];
        p += __shfl_xor(p, 1); p += __shfl_xor(p, 2);
        p += __shfl_xor(p, 4); p += __shfl_xor(p, 8);
        if (l15 == 0) gp[w][mt*16 + lhi*4 + r] = p;
      }
  }
  __syncthreads();   // A2 + gp complete
  if (tid < 64) gate_arr[tid] = bg2[0] + gp[0][tid] + gp[1][tid];

  // GEMM2 (R4-proven): val(64x128) = A2(64x128) @ Wn2 + bn2 ; wave w -> nt2 {2w,2w+1}
  const int nt2b = w*2;
  float bn2v[2];
  #pragma unroll
  for (int i=0;i<2;++i) bn2v[i] = bn2[(nt2b+i)*16 + l15];
  f4v acc2[4][2];
  #pragma unroll
  for (int mt=0;mt<4;++mt)
    #pragma unroll
    for (int i=0;i<2;++i) acc2[mt][i] = splat4(bn2v[i]);
  #pragma unroll
  for (int kb = 0; kb < 4; ++kb){
    bf8v a2f[4];
    #pragma unroll
    for (int mt=0;mt<4;++mt){
      int row = l15 + 16*mt;
      int off = row*256 + ((kb*64 + lhi*16) ^ ((row&7)<<4));
      a2f[mt] = *reinterpret_cast<const bf8v*>((const char*)A2 + off);
    }
    #pragma unroll
    for (int i=0;i<2;++i){
      bf8v b2f = *reinterpret_cast<const bf8v*>(wn2f + (((kb*8 + nt2b+i)*64 + lane)<<3));
      #pragma unroll
      for (int mt=0;mt<4;++mt) acc2[mt][i] = mfma16(a2f[mt], b2f, acc2[mt][i]);
    }
  }
  __syncthreads();  // gate_arr ready

  // phase D (R4-proven): block-local softmax partials (exact flash combine)
  float g = gate_arr[lane];
  float M = g;
  #pragma unroll
  for (int d=1; d<64; d<<=1) M = fmaxf(M, __shfl_xor(M, d));
  float e = ex2((g - M)*L2E);
  float sE = e;
  #pragma unroll
  for (int d=1; d<64; d<<=1) sE += __shfl_xor(sE, d);
  float ev0 = 0.f, ev1 = 0.f;
  #pragma unroll
  for (int mt=0;mt<4;++mt)
    #pragma unroll
    for (int r=0;r<4;++r){
      int row = mt*16 + lhi*4 + r;
      float wm = ex2((gate_arr[row] - M)*L2E);
      ev0 += wm*acc2[mt][0][r];
      ev1 += wm*acc2[mt][1][r];
    }
  ev0 += __shfl_xor(ev0, 16); ev0 += __shfl_xor(ev0, 32);
  ev1 += __shfl_xor(ev1, 16); ev1 += __shfl_xor(ev1, 32);

  float* pb = partials + (size_t)seq*130;
  if (tid == 0){ pb[0] = M; pb[1] = sE; }
  if (lane < 16){
    pb[2 + (nt2b+0)*16 + lane] = ev0;
    pb[2 + (nt2b+1)*16 + lane] = ev1;
  }
}

// ---------- combine: merge 64 partials per batch ----------
__global__ void combine_kernel(const float* __restrict__ partials, float* __restrict__ out)
{
  int b = blockIdx.x; int j = threadIdx.x;  // 128 threads
  const float* pb = partials + (size_t)b*64*130;
  float M = -3.0e38f;
  for (int p = 0; p < 64; ++p) M = fmaxf(M, pb[p*130]);
  float num = 0.f, den = 0.f;
  for (int p = 0; p < 64; ++p){
    float wm = ex2((pb[p*130] - M)*L2E);
    den += wm * pb[p*130 + 1];
    num += wm * pb[p*130 + 2 + j];
  }
  out[b*128 + j] = num / den;
}

// ---------- host ----------
extern "C" void kernel_launch(void* const* d_in, const int* in_sizes, int n_in,
                              void* d_out, int out_size, void* d_ws, size_t ws_size,
                              hipStream_t stream) {
  (void)in_sizes; (void)n_in; (void)out_size; (void)ws_size;
  const float* x     = (const float*)d_in[0];
  const float* W_emb = (const float*)d_in[1];
  const float* b_emb = (const float*)d_in[2];
  const float* W_ih  = (const float*)d_in[3];
  const float* W_hh  = (const float*)d_in[4];
  const float* b_ih  = (const float*)d_in[5];
  const float* b_hh  = (const float*)d_in[6];
  const float* Wg1   = (const float*)d_in[7];
  const float* bg1   = (const float*)d_in[8];
  const float* Wg2   = (const float*)d_in[9];
  const float* bg2   = (const float*)d_in[10];
  const float* Wn1   = (const float*)d_in[11];
  const float* bn1   = (const float*)d_in[12];
  const float* Wn2   = (const float*)d_in[13];
  const float* bn2   = (const float*)d_in[14];

  char* p = (char*)d_ws;
  short* bhhf    = (short*)p; p += 98304;
  short* wcxf    = (short*)p; p += 16384;
  short* wchf    = (short*)p; p += 65536;
  short* wn2f    = (short*)p; p += 32768;
  short* w2f     = (short*)p; p += 24576;
  float* b2      = (float*)p; p += 1536;
  short* xfrag   = (short*)p; p += 8388608;
  short* xf2     = (short*)p; p += 8388608;
  short* svb     = (short*)p; p += 4194304;
  float* rbf     = (float*)p; p += 65536;
  float* partials = (float*)p; p += (size_t)8192*130*4;

  prep_kernel<<<2578, 256, 0, stream>>>(x, W_emb, b_emb, W_ih, W_hh, b_ih,
                                        Wg1, Wn1, Wn2, bg1, bn1,
                                        bhhf, wcxf, wchf, wn2f, w2f, b2,
                                        xfrag, xf2, rbf);
  gru_kernel<<<512, 512, 0, stream>>>(xfrag, bhhf, w2f, b2, b_hh, wchf, svb);
  feats_kernel<<<8192, 256, 0, stream>>>(xf2, svb, rbf, wcxf, wn2f,
                                         Wg2, bg2, bn2, partials);
  combine_kernel<<<128, 128, 0, stream>>>(partials, (float*)d_out);
}

// Round 14
// 177.461 us; speedup vs baseline: 1.0159x; 1.0159x over previous
//
#include <hip/hip_runtime.h>

// ---------- types / helpers ----------
using bf8v = __bf16 __attribute__((ext_vector_type(8)));
using s4v  = short  __attribute__((ext_vector_type(4)));
using f4v  = float  __attribute__((ext_vector_type(4)));

#define L2E 1.44269504088896340f

__device__ __forceinline__ float ex2(float x){ float r; asm("v_exp_f32 %0, %1" : "=v"(r) : "v"(x)); return r; }
__device__ __forceinline__ float rcp_(float x){ float r; asm("v_rcp_f32 %0, %1" : "=v"(r) : "v"(x)); return r; }
__device__ __forceinline__ float sigm(float x){ return rcp_(1.0f + ex2(-L2E*x)); }
__device__ __forceinline__ float tanh_(float x){ return 1.0f - 2.0f*rcp_(1.0f + ex2(2.0f*L2E*x)); }
__device__ __forceinline__ short f2bf(float x){ return __builtin_bit_cast(short, (__bf16)x); }
__device__ __forceinline__ f4v splat4(float v){ f4v r = {v,v,v,v}; return r; }
__device__ __forceinline__ f4v mfma16(bf8v a, bf8v b, f4v c){
  return __builtin_amdgcn_mfma_f32_16x16x32_bf16(a, b, c, 0, 0, 0);
}
// paired reciprocal: {1/(1+e0), 1/(1+e1)} with ONE v_rcp per pair (saves 1 trans, +3 muls).
// Used in feats ONLY (high-TLP regime, R13: helped there, hurt latency-bound gru).
__device__ __forceinline__ float2 brcp2(float e0, float e1){
  float d0 = e0 + 1.0f, d1 = e1 + 1.0f;
  float inv = rcp_(d0*d1);
  return make_float2(d1*inv, d0*inv);
}

// ---------- prep: fragment-ize weights, fold W2/b2, x fragments, rowbias tail ----------
__global__ void prep_kernel(
    const float* __restrict__ x,
    const float* __restrict__ W_emb, const float* __restrict__ b_emb,
    const float* __restrict__ W_ih,  const float* __restrict__ W_hh,
    const float* __restrict__ b_ih,
    const float* __restrict__ Wg1,   const float* __restrict__ Wn1,
    const float* __restrict__ Wn2,
    const float* __restrict__ bg1,   const float* __restrict__ bn1,
    short* __restrict__ bhhf, short* __restrict__ wcxf, short* __restrict__ wchf,
    short* __restrict__ wn2f, short* __restrict__ w2f, float* __restrict__ b2,
    short* __restrict__ xfrag, short* __restrict__ xf2, float* __restrict__ rbf)
{
  __shared__ float pe_s[134];
  // ---- rb tail blocks: one block per t, rowbias in fragment layout ----
  if (blockIdx.x >= 2514){
    const int t = blockIdx.x - 2514;   // 0..63
    const int n = threadIdx.x;         // 0..255
    if (n < 134){
      float fr = expf(-(float)(n & ~1) * 9.210340371976184f / 134.f);
      float a = (float)t * fr;
      pe_s[n] = (n & 1) ? cosf(a) : sinf(a);
    }
    __syncthreads();
    float s = (n < 128) ? bg1[n] : bn1[n-128];
    const float* W = (n < 128) ? (Wg1 + n) : (Wn1 + (n-128));
    for (int k = 0; k < 134; ++k) s += pe_s[k] * W[(size_t)k*128];
    int mt = t>>4, lh = (t>>2)&3, r = t&3, nt = n>>4, l15 = n&15;
    rbf[(((nt*4 + mt)*64) + lh*16 + l15)*4 + r] = s;
    return;
  }

  int i = blockIdx.x*256 + threadIdx.x;
  if (i < 49152){ // W_hh fragments [kb4][nt24][lane][8]; B[k][n] = W_hh[n][k]
    int e = i&7, lane=(i>>3)&63, r=i>>9; int nt=r%24, kb=r/24;
    int k = kb*32 + ((lane>>4)<<3) + e;
    int n = nt*16 + (lane&15);
    bhhf[i] = f2bf(W_hh[n*128 + k]);
    return;
  }
  i -= 49152;
  if (i < 8192){ // Wcx B-fragments [nt16][lane][8]: rows k<6 of [Wg1|Wn1]; k>=6 zero (slot6 = seqvec at runtime)
    int e=i&7, lane=(i>>3)&63, nt=i>>9;
    int k = ((lane>>4)<<3) + e; int n = nt*16 + (lane&15);
    float v = 0.f;
    if (k < 6) v = (n < 128) ? Wg1[k*128 + n] : Wn1[k*128 + (n-128)];
    wcxf[i] = f2bf(v);
    return;
  }
  i -= 8192;
  if (i < 32768){ // Wch B-fragments [kb4][nt16][lane][8]: rows 6..133 of [Wg1|Wn1] (K=128 exact)
    int e=i&7, lane=(i>>3)&63, r=i>>9; int nt=r&15, kb=r>>4;
    int k = 6 + kb*32 + ((lane>>4)<<3) + e; int n = nt*16 + (lane&15);
    float v = (n < 128) ? Wg1[k*128 + n] : Wn1[k*128 + (n-128)];
    wchf[i] = f2bf(v);
    return;
  }
  i -= 32768;
  if (i < 16384){ // Wn2 B-fragments [kb4][nt8][lane][8]
    int e=i&7, lane=(i>>3)&63, r=i>>9; int nt=r%8, kb=r/8;
    int k = kb*32 + ((lane>>4)<<3) + e; int n = nt*16 + (lane&15);
    wn2f[i] = f2bf(Wn2[k*128 + n]);
    return;
  }
  i -= 16384;
  if (i < 12288){ // W2 = W_emb @ W_ih^T B-fragments [nt24][lane][8], K=32 (rows>=6 zero)
    int e=i&7, lane=(i>>3)&63, nt=i>>9;
    int k = ((lane>>4)<<3) + e; int n = nt*16 + (lane&15);
    float v = 0.f;
    if (k < 6){
      const float* we = W_emb + k*128; const float* wi = W_ih + n*128;
      float s = 0.f;
      for (int h2=0; h2<128; ++h2) s += we[h2]*wi[h2];
      v = s;
    }
    w2f[i] = f2bf(v);
    return;
  }
  i -= 12288;
  if (i < 384){ // b2 = b_ih + b_emb @ W_ih^T
    float s = b_ih[i]; const float* wi = W_ih + i*128;
    for (int h2=0; h2<128; ++h2) s += b_emb[h2]*wi[h2];
    b2[i] = s;
    return;
  }
  i -= 384;
  if (i < 524288){ // x fragments, lane = t for coalesced reads
    int t = i & 63, r = (i>>6)&15, grp = i>>10;
    const float* xr = x + ((size_t)(grp*16 + r)*64 + t)*6;
    s4v lo, hi;
    lo[0]=f2bf(xr[0]); lo[1]=f2bf(xr[1]); lo[2]=f2bf(xr[2]); lo[3]=f2bf(xr[3]);
    hi[0]=f2bf(xr[4]); hi[1]=f2bf(xr[5]); hi[2]=f2bf(1.0f); hi[3]=0;
    // gru layout: xfrag[grp][t][r][8]
    size_t o1 = ((size_t)(grp*64 + t)*16 + r)*8;
    *reinterpret_cast<s4v*>(xfrag + o1)     = lo;
    *reinterpret_cast<s4v*>(xfrag + o1 + 4) = hi;
    // feats layout: xf2[seq][t][8]
    size_t o2 = ((size_t)(grp*16 + r)*64 + t)*8;
    *reinterpret_cast<s4v*>(xf2 + o2)     = lo;
    *reinterpret_cast<s4v*>(xf2 + o2 + 4) = hi;
    return;
  }
}

// ---------- GRU: 16 seqs/block, 1 stream; 8 waves; 512 blocks (2/CU -> 4 waves/SIMD) ----------
// Latency-bound (R13 lesson): combined-denominator gate math, 5 trans/element, rows independent.
// h' = [en*(ez+h) + (h-ez)] / [(1+en)(1+ez)]  ==  n + z*(h-n), exact.
__global__ __launch_bounds__(512, 4) void gru_kernel(
    const short* __restrict__ xfrag,   // [512][64][16][8]
    const short* __restrict__ bhhf,    // [4][24][64][8]
    const short* __restrict__ w2f,     // [24][64][8]
    const float* __restrict__ b2,      // 384
    const float* __restrict__ b_hh,    // 384
    const short* __restrict__ wchf,    // [4][16][64][8]
    short* __restrict__ svb)           // (8192,256) bf16
{
  __shared__ alignas(16) short h_lds[2][16*128];  // [dbuf], XOR-swizzled rows
  const int tid = threadIdx.x;
  const int w = tid >> 6;
  const int lane = tid & 63;
  const int l15 = lane & 15, lhi = lane >> 4;
  const int blk = blockIdx.x;

  for (int i = tid; i < 16*128; i += 512) h_lds[0][i] = 0;

  // hoisted B fragments + biases
  bf8v bhh[4][3]; bf8v w2v[3];
  float b2v[3], bhv[3];
  #pragma unroll
  for (int g = 0; g < 3; ++g){
    int nt = g*8 + w;
    w2v[g] = *reinterpret_cast<const bf8v*>(w2f + ((nt*64 + lane)<<3));
    #pragma unroll
    for (int kb = 0; kb < 4; ++kb)
      bhh[kb][g] = *reinterpret_cast<const bf8v*>(bhhf + (((kb*24 + nt)*64 + lane)<<3));
    int col = nt*16 + l15;
    b2v[g] = b2[col]; bhv[g] = b_hh[col];
  }
  float hr0[4] = {0.f,0.f,0.f,0.f};
  __syncthreads();

  const short* xf0 = xfrag + (size_t)blk*8192 + l15*8;
  const int sw_r = (l15 & 7) << 4;

  bf8v ax0 = *reinterpret_cast<const bf8v*>(xf0);

#define GSTEP(P, T)                                                           \
  {                                                                           \
    int tn = (T) + 1; if (tn > 63) tn = 63;                                   \
    bf8v axn0 = *reinterpret_cast<const bf8v*>(xf0 + tn*128);                 \
    bf8v ah0[4];                                                              \
    _Pragma("unroll")                                                         \
    for (int kb = 0; kb < 4; ++kb){                                           \
      int off = l15*256 + ((kb*64 + lhi*16) ^ sw_r);                          \
      ah0[kb] = *reinterpret_cast<const bf8v*>((const char*)h_lds[P] + off);  \
    }                                                                         \
    f4v xg0[3], gh0[3];                                                       \
    _Pragma("unroll")                                                         \
    for (int g = 0; g < 3; ++g){                                              \
      xg0[g] = splat4(b2v[g]); xg0[g] = mfma16(ax0, w2v[g], xg0[g]);          \
      gh0[g] = splat4(bhv[g]);                                                \
      _Pragma("unroll")                                                       \
      for (int kb = 0; kb < 4; ++kb)                                          \
        gh0[g] = mfma16(ah0[kb], bhh[kb][g], gh0[g]);                         \
    }                                                                         \
    _Pragma("unroll")                                                         \
    for (int r = 0; r < 4; ++r){                                              \
      int s = lhi*4 + r;                                                      \
      int woff = s*256 + (((w*16 + l15)*2) ^ ((s&7)<<4));                     \
      float er = ex2(-L2E*(xg0[0][r] + gh0[0][r]));                           \
      float ez = ex2(-L2E*(xg0[1][r] + gh0[1][r]));                           \
      float rg = rcp_(1.0f + er);                                             \
      float en = ex2(2.0f*L2E*(xg0[2][r] + rg*gh0[2][r]));                    \
      float h  = hr0[r];                                                      \
      float num = en*(ez + h) + (h - ez);                                     \
      float den = (1.0f + en)*(1.0f + ez);                                    \
      float hv = num * rcp_(den);                                             \
      hr0[r] = hv;                                                            \
      *(short*)((char*)h_lds[P^1] + woff) = f2bf(hv);                         \
    }                                                                         \
    ax0 = axn0;                                                               \
    __syncthreads();                                                          \
  }

  for (int tt = 0; tt < 32; ++tt){
    GSTEP(0, 2*tt);
    GSTEP(1, 2*tt + 1);
  }
#undef GSTEP

  // ---- seqvec epilogue (PROVEN orientation): A = h frag (rows=seq), B = Wch frag (cols=n).
  {
    bf8v ah[4];
    #pragma unroll
    for (int kb = 0; kb < 4; ++kb){
      int off = l15*256 + ((kb*64 + lhi*16) ^ sw_r);
      ah[kb] = *reinterpret_cast<const bf8v*>((const char*)h_lds[0] + off);
    }
    #pragma unroll
    for (int j = 0; j < 2; ++j){
      int nt = w*2 + j;
      f4v a = {0.f,0.f,0.f,0.f};
      #pragma unroll
      for (int kb = 0; kb < 4; ++kb){
        bf8v wf = *reinterpret_cast<const bf8v*>(wchf + (((kb*16 + nt)*64 + lane)<<3));
        a = mfma16(ah[kb], wf, a);
      }
      #pragma unroll
      for (int r = 0; r < 4; ++r){
        int sq = blk*16 + lhi*4 + r;
        svb[(size_t)sq*256 + nt*16 + l15] = f2bf(a[r]);
      }
    }
  }
}

// ---------- feats: K=32 GEMM1 (x + seqvec slot) + rbf C-init, PROVEN orientation ----------
// launch_bounds(256,6); silu uses brcp2 pairs (kept from R13: helped in this high-TLP regime).
__global__ __launch_bounds__(256, 6) void feats_kernel(
    const short* __restrict__ xf2, const short* __restrict__ svb,
    const float* __restrict__ rbf,
    const short* __restrict__ wcxf, const short* __restrict__ wn2f,
    const float* __restrict__ Wg2, const float* __restrict__ bg2,
    const float* __restrict__ bn2,
    float* __restrict__ partials)  // [8192][130] = {max, sumE, sumEV[128]}
{
  __shared__ alignas(16) short A2[64*128];  // silu val-hidden, bf16, XOR-swizzled (16KB)
  __shared__ float gp[2][64];
  __shared__ float gate_arr[64];

  const int tid = threadIdx.x;
  const int w = tid >> 6;
  const int lane = tid & 63;
  const int l15 = lane & 15, lhi = lane >> 4;
  const int seq = blockIdx.x;
  const int ntb = w*4;

  // x A-fragments (rows = t); only lhi==0 lanes carry data (k = 0..7)
  bf8v bx[4];
  #pragma unroll
  for (int mt=0;mt<4;++mt){
    bf8v z;
    #pragma unroll
    for (int e=0;e<8;++e) z[e] = (__bf16)0.f;
    bx[mt] = z;
  }
  if (lhi == 0){
    const short* xp = xf2 + (size_t)seq*512;
    #pragma unroll
    for (int mt=0;mt<4;++mt)
      bx[mt] = *reinterpret_cast<const bf8v*>(xp + (mt*16 + l15)*8);
  }

  float gd[4][4];
  #pragma unroll
  for (int mt=0;mt<4;++mt)
    #pragma unroll
    for (int r=0;r<4;++r) gd[mt][r] = 0.f;

  #pragma unroll
  for (int i = 0; i < 4; ++i){
    const int n16 = (ntb+i)*16;
    bf8v wb = *reinterpret_cast<const bf8v*>(wcxf + (((ntb+i)*64 + lane)<<3));
    if (lhi == 0)
      wb[6] = __builtin_bit_cast(__bf16, svb[(size_t)seq*256 + n16 + l15]);
    f4v acc[4];
    #pragma unroll
    for (int mt=0;mt<4;++mt){
      acc[mt] = *reinterpret_cast<const f4v*>(rbf + (((ntb+i)*4 + mt)*64 + lane)*4);
      acc[mt] = mfma16(bx[mt], wb, acc[mt]);
    }
    // acc[mt][r]: hidden[m = mt*16 + lhi*4 + r][n = n16 + l15]
    if (w < 2){
      float wg2s = Wg2[n16 + l15];
      #pragma unroll
      for (int mt=0;mt<4;++mt){
        f4v e, o;
        #pragma unroll
        for (int r=0;r<4;++r) e[r] = ex2(-L2E*acc[mt][r]);
        float2 q0 = brcp2(e[0], e[1]); o[0] = q0.x; o[1] = q0.y;
        float2 q1 = brcp2(e[2], e[3]); o[2] = q1.x; o[3] = q1.y;
        #pragma unroll
        for (int r=0;r<4;++r) gd[mt][r] += acc[mt][r]*o[r]*wg2s;
      }
    } else {
      #pragma unroll
      for (int mt=0;mt<4;++mt){
        f4v e, o;
        #pragma unroll
        for (int r=0;r<4;++r) e[r] = ex2(-L2E*acc[mt][r]);
        float2 q0 = brcp2(e[0], e[1]); o[0] = q0.x; o[1] = q0.y;
        float2 q1 = brcp2(e[2], e[3]); o[2] = q1.x; o[3] = q1.y;
        #pragma unroll
        for (int r=0;r<4;++r){
          float s = acc[mt][r]*o[r];
          int row = mt*16 + lhi*4 + r;
          int colb = (((w-2)*4 + i)*16 + l15)*2;
          int off = row*256 + (colb ^ ((row&7)<<4));
          *(short*)((char*)A2 + off) = f2bf(s);
        }
      }
    }
  }
  if (w < 2){
    #pragma unroll
    for (int mt=0;mt<4;++mt)
      #pragma unroll
      for (int r=0;r<4;++r){
        float p = gd[mt][r];
        p += __shfl_xor(p, 1); p += __shfl_xor(p, 2);
        p += __shfl_xor(p, 4); p += __shfl_xor(p, 8);
        if (l15 == 0) gp[w][mt*16 + lhi*4 + r] = p;
      }
  }
  __syncthreads();   // A2 + gp complete
  if (tid < 64) gate_arr[tid] = bg2[0] + gp[0][tid] + gp[1][tid];

  // GEMM2 (R4-proven): val(64x128) = A2(64x128) @ Wn2 + bn2 ; wave w -> nt2 {2w,2w+1}
  const int nt2b = w*2;
  float bn2v[2];
  #pragma unroll
  for (int i=0;i<2;++i) bn2v[i] = bn2[(nt2b+i)*16 + l15];
  f4v acc2[4][2];
  #pragma unroll
  for (int mt=0;mt<4;++mt)
    #pragma unroll
    for (int i=0;i<2;++i) acc2[mt][i] = splat4(bn2v[i]);
  #pragma unroll
  for (int kb = 0; kb < 4; ++kb){
    bf8v a2f[4];
    #pragma unroll
    for (int mt=0;mt<4;++mt){
      int row = l15 + 16*mt;
      int off = row*256 + ((kb*64 + lhi*16) ^ ((row&7)<<4));
      a2f[mt] = *reinterpret_cast<const bf8v*>((const char*)A2 + off);
    }
    #pragma unroll
    for (int i=0;i<2;++i){
      bf8v b2f = *reinterpret_cast<const bf8v*>(wn2f + (((kb*8 + nt2b+i)*64 + lane)<<3));
      #pragma unroll
      for (int mt=0;mt<4;++mt) acc2[mt][i] = mfma16(a2f[mt], b2f, acc2[mt][i]);
    }
  }
  __syncthreads();  // gate_arr ready

  // phase D (R4-proven): block-local softmax partials (exact flash combine)
  float g = gate_arr[lane];
  float M = g;
  #pragma unroll
  for (int d=1; d<64; d<<=1) M = fmaxf(M, __shfl_xor(M, d));
  float e = ex2((g - M)*L2E);
  float sE = e;
  #pragma unroll
  for (int d=1; d<64; d<<=1) sE += __shfl_xor(sE, d);
  float ev0 = 0.f, ev1 = 0.f;
  #pragma unroll
  for (int mt=0;mt<4;++mt)
    #pragma unroll
    for (int r=0;r<4;++r){
      int row = mt*16 + lhi*4 + r;
      float wm = ex2((gate_arr[row] - M)*L2E);
      ev0 += wm*acc2[mt][0][r];
      ev1 += wm*acc2[mt][1][r];
    }
  ev0 += __shfl_xor(ev0, 16); ev0 += __shfl_xor(ev0, 32);
  ev1 += __shfl_xor(ev1, 16); ev1 += __shfl_xor(ev1, 32);

  float* pb = partials + (size_t)seq*130;
  if (tid == 0){ pb[0] = M; pb[1] = sE; }
  if (lane < 16){
    pb[2 + (nt2b+0)*16 + lane] = ev0;
    pb[2 + (nt2b+1)*16 + lane] = ev1;
  }
}

// ---------- combine: merge 64 partials per batch ----------
__global__ void combine_kernel(const float* __restrict__ partials, float* __restrict__ out)
{
  int b = blockIdx.x; int j = threadIdx.x;  // 128 threads
  const float* pb = partials + (size_t)b*64*130;
  float M = -3.0e38f;
  for (int p = 0; p < 64; ++p) M = fmaxf(M, pb[p*130]);
  float num = 0.f, den = 0.f;
  for (int p = 0; p < 64; ++p){
    float wm = ex2((pb[p*130] - M)*L2E);
    den += wm * pb[p*130 + 1];
    num += wm * pb[p*130 + 2 + j];
  }
  out[b*128 + j] = num / den;
}

// ---------- host ----------
extern "C" void kernel_launch(void* const* d_in, const int* in_sizes, int n_in,
                              void* d_out, int out_size, void* d_ws, size_t ws_size,
                              hipStream_t stream) {
  (void)in_sizes; (void)n_in; (void)out_size; (void)ws_size;
  const float* x     = (const float*)d_in[0];
  const float* W_emb = (const float*)d_in[1];
  const float* b_emb = (const float*)d_in[2];
  const float* W_ih  = (const float*)d_in[3];
  const float* W_hh  = (const float*)d_in[4];
  const float* b_ih  = (const float*)d_in[5];
  const float* b_hh  = (const float*)d_in[6];
  const float* Wg1   = (const float*)d_in[7];
  const float* bg1   = (const float*)d_in[8];
  const float* Wg2   = (const float*)d_in[9];
  const float* bg2   = (const float*)d_in[10];
  const float* Wn1   = (const float*)d_in[11];
  const float* bn1   = (const float*)d_in[12];
  const float* Wn2   = (const float*)d_in[13];
  const float* bn2   = (const float*)d_in[14];

  char* p = (char*)d_ws;
  short* bhhf    = (short*)p; p += 98304;
  short* wcxf    = (short*)p; p += 16384;
  short* wchf    = (short*)p; p += 65536;
  short* wn2f    = (short*)p; p += 32768;
  short* w2f     = (short*)p; p += 24576;
  float* b2      = (float*)p; p += 1536;
  short* xfrag   = (short*)p; p += 8388608;
  short* xf2     = (short*)p; p += 8388608;
  short* svb     = (short*)p; p += 4194304;
  float* rbf     = (float*)p; p += 65536;
  float* partials = (float*)p; p += (size_t)8192*130*4;

  prep_kernel<<<2578, 256, 0, stream>>>(x, W_emb, b_emb, W_ih, W_hh, b_ih,
                                        Wg1, Wn1, Wn2, bg1, bn1,
                                        bhhf, wcxf, wchf, wn2f, w2f, b2,
                                        xfrag, xf2, rbf);
  gru_kernel<<<512, 512, 0, stream>>>(xfrag, bhhf, w2f, b2, b_hh, wchf, svb);
  feats_kernel<<<8192, 256, 0, stream>>>(xf2, svb, rbf, wcxf, wn2f,
                                         Wg2, bg2, bn2, partials);
  combine_kernel<<<128, 128, 0, stream>>>(partials, (float*)d_out);
}

// Round 15
// 174.715 us; speedup vs baseline: 1.0318x; 1.0157x over previous
//
#include <hip/hip_runtime.h>

// ---------- types / helpers ----------
using bf8v = __bf16 __attribute__((ext_vector_type(8)));
using s4v  = short  __attribute__((ext_vector_type(4)));
using f4v  = float  __attribute__((ext_vector_type(4)));

#define L2E 1.44269504088896340f

__device__ __forceinline__ float ex2(float x){ float r; asm("v_exp_f32 %0, %1" : "=v"(r) : "v"(x)); return r; }
__device__ __forceinline__ float rcp_(float x){ float r; asm("v_rcp_f32 %0, %1" : "=v"(r) : "v"(x)); return r; }
__device__ __forceinline__ float sigm(float x){ return rcp_(1.0f + ex2(-L2E*x)); }
__device__ __forceinline__ float tanh_(float x){ return 1.0f - 2.0f*rcp_(1.0f + ex2(2.0f*L2E*x)); }
__device__ __forceinline__ short f2bf(float x){ return __builtin_bit_cast(short, (__bf16)x); }
__device__ __forceinline__ f4v splat4(float v){ f4v r = {v,v,v,v}; return r; }
__device__ __forceinline__ f4v mfma16(bf8v a, bf8v b, f4v c){
  return __builtin_amdgcn_mfma_f32_16x16x32_bf16(a, b, c, 0, 0, 0);
}
// paired reciprocal: {1/(1+e0), 1/(1+e1)} with ONE v_rcp per pair (saves 1 trans, +3 muls).
// Used in feats ONLY (high-TLP regime, R13: helped there; hurt latency-bound gru R10/R13/R14).
__device__ __forceinline__ float2 brcp2(float e0, float e1){
  float d0 = e0 + 1.0f, d1 = e1 + 1.0f;
  float inv = rcp_(d0*d1);
  return make_float2(d1*inv, d0*inv);
}

// ---------- prep: fragment-ize weights, fold W2/b2, x fragments, rowbias tail ----------
__global__ void prep_kernel(
    const float* __restrict__ x,
    const float* __restrict__ W_emb, const float* __restrict__ b_emb,
    const float* __restrict__ W_ih,  const float* __restrict__ W_hh,
    const float* __restrict__ b_ih,
    const float* __restrict__ Wg1,   const float* __restrict__ Wn1,
    const float* __restrict__ Wn2,
    const float* __restrict__ bg1,   const float* __restrict__ bn1,
    short* __restrict__ bhhf, short* __restrict__ wcxf, short* __restrict__ wchf,
    short* __restrict__ wn2f, short* __restrict__ w2f, float* __restrict__ b2,
    short* __restrict__ xfrag, short* __restrict__ xf2, float* __restrict__ rbf)
{
  __shared__ float pe_s[134];
  // ---- rb tail blocks: one block per t, rowbias in fragment layout ----
  if (blockIdx.x >= 2514){
    const int t = blockIdx.x - 2514;   // 0..63
    const int n = threadIdx.x;         // 0..255
    if (n < 134){
      float fr = expf(-(float)(n & ~1) * 9.210340371976184f / 134.f);
      float a = (float)t * fr;
      pe_s[n] = (n & 1) ? cosf(a) : sinf(a);
    }
    __syncthreads();
    float s = (n < 128) ? bg1[n] : bn1[n-128];
    const float* W = (n < 128) ? (Wg1 + n) : (Wn1 + (n-128));
    for (int k = 0; k < 134; ++k) s += pe_s[k] * W[(size_t)k*128];
    int mt = t>>4, lh = (t>>2)&3, r = t&3, nt = n>>4, l15 = n&15;
    rbf[(((nt*4 + mt)*64) + lh*16 + l15)*4 + r] = s;
    return;
  }

  int i = blockIdx.x*256 + threadIdx.x;
  if (i < 49152){ // W_hh fragments [kb4][nt24][lane][8]; B[k][n] = W_hh[n][k]
    int e = i&7, lane=(i>>3)&63, r=i>>9; int nt=r%24, kb=r/24;
    int k = kb*32 + ((lane>>4)<<3) + e;
    int n = nt*16 + (lane&15);
    bhhf[i] = f2bf(W_hh[n*128 + k]);
    return;
  }
  i -= 49152;
  if (i < 8192){ // Wcx B-fragments [nt16][lane][8]: rows k<6 of [Wg1|Wn1]; k>=6 zero (slot6 = seqvec at runtime)
    int e=i&7, lane=(i>>3)&63, nt=i>>9;
    int k = ((lane>>4)<<3) + e; int n = nt*16 + (lane&15);
    float v = 0.f;
    if (k < 6) v = (n < 128) ? Wg1[k*128 + n] : Wn1[k*128 + (n-128)];
    wcxf[i] = f2bf(v);
    return;
  }
  i -= 8192;
  if (i < 32768){ // Wch B-fragments [kb4][nt16][lane][8]: rows 6..133 of [Wg1|Wn1] (K=128 exact)
    int e=i&7, lane=(i>>3)&63, r=i>>9; int nt=r&15, kb=r>>4;
    int k = 6 + kb*32 + ((lane>>4)<<3) + e; int n = nt*16 + (lane&15);
    float v = (n < 128) ? Wg1[k*128 + n] : Wn1[k*128 + (n-128)];
    wchf[i] = f2bf(v);
    return;
  }
  i -= 32768;
  if (i < 16384){ // Wn2 B-fragments [kb4][nt8][lane][8]
    int e=i&7, lane=(i>>3)&63, r=i>>9; int nt=r%8, kb=r/8;
    int k = kb*32 + ((lane>>4)<<3) + e; int n = nt*16 + (lane&15);
    wn2f[i] = f2bf(Wn2[k*128 + n]);
    return;
  }
  i -= 16384;
  if (i < 12288){ // W2 = W_emb @ W_ih^T B-fragments [nt24][lane][8], K=32 (rows>=6 zero)
    int e=i&7, lane=(i>>3)&63, nt=i>>9;
    int k = ((lane>>4)<<3) + e; int n = nt*16 + (lane&15);
    float v = 0.f;
    if (k < 6){
      const float* we = W_emb + k*128; const float* wi = W_ih + n*128;
      float s = 0.f;
      for (int h2=0; h2<128; ++h2) s += we[h2]*wi[h2];
      v = s;
    }
    w2f[i] = f2bf(v);
    return;
  }
  i -= 12288;
  if (i < 384){ // b2 = b_ih + b_emb @ W_ih^T
    float s = b_ih[i]; const float* wi = W_ih + i*128;
    for (int h2=0; h2<128; ++h2) s += b_emb[h2]*wi[h2];
    b2[i] = s;
    return;
  }
  i -= 384;
  if (i < 524288){ // x fragments, lane = t for coalesced reads
    int t = i & 63, r = (i>>6)&15, grp = i>>10;
    const float* xr = x + ((size_t)(grp*16 + r)*64 + t)*6;
    s4v lo, hi;
    lo[0]=f2bf(xr[0]); lo[1]=f2bf(xr[1]); lo[2]=f2bf(xr[2]); lo[3]=f2bf(xr[3]);
    hi[0]=f2bf(xr[4]); hi[1]=f2bf(xr[5]); hi[2]=f2bf(1.0f); hi[3]=0;
    // gru layout: xfrag[grp][t][r][8]
    size_t o1 = ((size_t)(grp*64 + t)*16 + r)*8;
    *reinterpret_cast<s4v*>(xfrag + o1)     = lo;
    *reinterpret_cast<s4v*>(xfrag + o1 + 4) = hi;
    // feats layout: xf2[seq][t][8]
    size_t o2 = ((size_t)(grp*16 + r)*64 + t)*8;
    *reinterpret_cast<s4v*>(xf2 + o2)     = lo;
    *reinterpret_cast<s4v*>(xf2 + o2 + 4) = hi;
    return;
  }
}

// ---------- GRU: 16 seqs/block, 1 stream; 8 waves; 512 blocks (2/CU -> 4 waves/SIMD) ----------
// R11 gate math (plain sigm/tanh, independent rows) — proven optimum; trans-reduction
// variants (R10 brcp4, R13 brcp2, R14 combined-denom) all regressed at ~95% issue saturation.
__global__ __launch_bounds__(512, 4) void gru_kernel(
    const short* __restrict__ xfrag,   // [512][64][16][8]
    const short* __restrict__ bhhf,    // [4][24][64][8]
    const short* __restrict__ w2f,     // [24][64][8]
    const float* __restrict__ b2,      // 384
    const float* __restrict__ b_hh,    // 384
    const short* __restrict__ wchf,    // [4][16][64][8]
    short* __restrict__ svb)           // (8192,256) bf16
{
  __shared__ alignas(16) short h_lds[2][16*128];  // [dbuf], XOR-swizzled rows
  const int tid = threadIdx.x;
  const int w = tid >> 6;
  const int lane = tid & 63;
  const int l15 = lane & 15, lhi = lane >> 4;
  const int blk = blockIdx.x;

  for (int i = tid; i < 16*128; i += 512) h_lds[0][i] = 0;

  // hoisted B fragments + biases
  bf8v bhh[4][3]; bf8v w2v[3];
  float b2v[3], bhv[3];
  #pragma unroll
  for (int g = 0; g < 3; ++g){
    int nt = g*8 + w;
    w2v[g] = *reinterpret_cast<const bf8v*>(w2f + ((nt*64 + lane)<<3));
    #pragma unroll
    for (int kb = 0; kb < 4; ++kb)
      bhh[kb][g] = *reinterpret_cast<const bf8v*>(bhhf + (((kb*24 + nt)*64 + lane)<<3));
    int col = nt*16 + l15;
    b2v[g] = b2[col]; bhv[g] = b_hh[col];
  }
  float hr0[4] = {0.f,0.f,0.f,0.f};
  __syncthreads();

  const short* xf0 = xfrag + (size_t)blk*8192 + l15*8;
  const int sw_r = (l15 & 7) << 4;

  bf8v ax0 = *reinterpret_cast<const bf8v*>(xf0);

#define GSTEP(P, T)                                                           \
  {                                                                           \
    int tn = (T) + 1; if (tn > 63) tn = 63;                                   \
    bf8v axn0 = *reinterpret_cast<const bf8v*>(xf0 + tn*128);                 \
    bf8v ah0[4];                                                              \
    _Pragma("unroll")                                                         \
    for (int kb = 0; kb < 4; ++kb){                                           \
      int off = l15*256 + ((kb*64 + lhi*16) ^ sw_r);                          \
      ah0[kb] = *reinterpret_cast<const bf8v*>((const char*)h_lds[P] + off);  \
    }                                                                         \
    f4v xg0[3], gh0[3];                                                       \
    _Pragma("unroll")                                                         \
    for (int g = 0; g < 3; ++g){                                              \
      xg0[g] = splat4(b2v[g]); xg0[g] = mfma16(ax0, w2v[g], xg0[g]);          \
      gh0[g] = splat4(bhv[g]);                                                \
      _Pragma("unroll")                                                       \
      for (int kb = 0; kb < 4; ++kb)                                          \
        gh0[g] = mfma16(ah0[kb], bhh[kb][g], gh0[g]);                         \
    }                                                                         \
    _Pragma("unroll")                                                         \
    for (int r = 0; r < 4; ++r){                                              \
      int s = lhi*4 + r;                                                      \
      int woff = s*256 + (((w*16 + l15)*2) ^ ((s&7)<<4));                     \
      float rg = sigm(xg0[0][r] + gh0[0][r]);                                 \
      float zg = sigm(xg0[1][r] + gh0[1][r]);                                 \
      float ng = tanh_(xg0[2][r] + rg*gh0[2][r]);                             \
      float hv = ng + zg*(hr0[r] - ng); hr0[r] = hv;                          \
      *(short*)((char*)h_lds[P^1] + woff) = f2bf(hv);                         \
    }                                                                         \
    ax0 = axn0;                                                               \
    __syncthreads();                                                          \
  }

  for (int tt = 0; tt < 32; ++tt){
    GSTEP(0, 2*tt);
    GSTEP(1, 2*tt + 1);
  }
#undef GSTEP

  // ---- seqvec epilogue (PROVEN orientation): A = h frag (rows=seq), B = Wch frag (cols=n).
  {
    bf8v ah[4];
    #pragma unroll
    for (int kb = 0; kb < 4; ++kb){
      int off = l15*256 + ((kb*64 + lhi*16) ^ sw_r);
      ah[kb] = *reinterpret_cast<const bf8v*>((const char*)h_lds[0] + off);
    }
    #pragma unroll
    for (int j = 0; j < 2; ++j){
      int nt = w*2 + j;
      f4v a = {0.f,0.f,0.f,0.f};
      #pragma unroll
      for (int kb = 0; kb < 4; ++kb){
        bf8v wf = *reinterpret_cast<const bf8v*>(wchf + (((kb*16 + nt)*64 + lane)<<3));
        a = mfma16(ah[kb], wf, a);
      }
      #pragma unroll
      for (int r = 0; r < 4; ++r){
        int sq = blk*16 + lhi*4 + r;
        svb[(size_t)sq*256 + nt*16 + l15] = f2bf(a[r]);
      }
    }
  }
}

// ---------- feats: K=32 GEMM1 (x + seqvec slot) + rbf C-init, PROVEN orientation ----------
// launch_bounds(256,6); silu uses brcp2 pairs (kept from R13: helped in this high-TLP regime).
__global__ __launch_bounds__(256, 6) void feats_kernel(
    const short* __restrict__ xf2, const short* __restrict__ svb,
    const float* __restrict__ rbf,
    const short* __restrict__ wcxf, const short* __restrict__ wn2f,
    const float* __restrict__ Wg2, const float* __restrict__ bg2,
    const float* __restrict__ bn2,
    float* __restrict__ partials)  // [8192][130] = {max, sumE, sumEV[128]}
{
  __shared__ alignas(16) short A2[64*128];  // silu val-hidden, bf16, XOR-swizzled (16KB)
  __shared__ float gp[2][64];
  __shared__ float gate_arr[64];

  const int tid = threadIdx.x;
  const int w = tid >> 6;
  const int lane = tid & 63;
  const int l15 = lane & 15, lhi = lane >> 4;
  const int seq = blockIdx.x;
  const int ntb = w*4;

  // x A-fragments (rows = t); only lhi==0 lanes carry data (k = 0..7)
  bf8v bx[4];
  #pragma unroll
  for (int mt=0;mt<4;++mt){
    bf8v z;
    #pragma unroll
    for (int e=0;e<8;++e) z[e] = (__bf16)0.f;
    bx[mt] = z;
  }
  if (lhi == 0){
    const short* xp = xf2 + (size_t)seq*512;
    #pragma unroll
    for (int mt=0;mt<4;++mt)
      bx[mt] = *reinterpret_cast<const bf8v*>(xp + (mt*16 + l15)*8);
  }

  float gd[4][4];
  #pragma unroll
  for (int mt=0;mt<4;++mt)
    #pragma unroll
    for (int r=0;r<4;++r) gd[mt][r] = 0.f;

  #pragma unroll
  for (int i = 0; i < 4; ++i){
    const int n16 = (ntb+i)*16;
    bf8v wb = *reinterpret_cast<const bf8v*>(wcxf + (((ntb+i)*64 + lane)<<3));
    if (lhi == 0)
      wb[6] = __builtin_bit_cast(__bf16, svb[(size_t)seq*256 + n16 + l15]);
    f4v acc[4];
    #pragma unroll
    for (int mt=0;mt<4;++mt){
      acc[mt] = *reinterpret_cast<const f4v*>(rbf + (((ntb+i)*4 + mt)*64 + lane)*4);
      acc[mt] = mfma16(bx[mt], wb, acc[mt]);
    }
    // acc[mt][r]: hidden[m = mt*16 + lhi*4 + r][n = n16 + l15]
    if (w < 2){
      float wg2s = Wg2[n16 + l15];
      #pragma unroll
      for (int mt=0;mt<4;++mt){
        f4v e, o;
        #pragma unroll
        for (int r=0;r<4;++r) e[r] = ex2(-L2E*acc[mt][r]);
        float2 q0 = brcp2(e[0], e[1]); o[0] = q0.x; o[1] = q0.y;
        float2 q1 = brcp2(e[2], e[3]); o[2] = q1.x; o[3] = q1.y;
        #pragma unroll
        for (int r=0;r<4;++r) gd[mt][r] += acc[mt][r]*o[r]*wg2s;
      }
    } else {
      #pragma unroll
      for (int mt=0;mt<4;++mt){
        f4v e, o;
        #pragma unroll
        for (int r=0;r<4;++r) e[r] = ex2(-L2E*acc[mt][r]);
        float2 q0 = brcp2(e[0], e[1]); o[0] = q0.x; o[1] = q0.y;
        float2 q1 = brcp2(e[2], e[3]); o[2] = q1.x; o[3] = q1.y;
        #pragma unroll
        for (int r=0;r<4;++r){
          float s = acc[mt][r]*o[r];
          int row = mt*16 + lhi*4 + r;
          int colb = (((w-2)*4 + i)*16 + l15)*2;
          int off = row*256 + (colb ^ ((row&7)<<4));
          *(short*)((char*)A2 + off) = f2bf(s);
        }
      }
    }
  }
  if (w < 2){
    #pragma unroll
    for (int mt=0;mt<4;++mt)
      #pragma unroll
      for (int r=0;r<4;++r){
        float p = gd[mt][r];
        p += __shfl_xor(p, 1); p += __shfl_xor(p, 2);
        p += __shfl_xor(p, 4); p += __shfl_xor(p, 8);
        if (l15 == 0) gp[w][mt*16 + lhi*4 + r] = p;
      }
  }
  __syncthreads();   // A2 + gp complete
  if (tid < 64) gate_arr[tid] = bg2[0] + gp[0][tid] + gp[1][tid];

  // GEMM2 (R4-proven): val(64x128) = A2(64x128) @ Wn2 + bn2 ; wave w -> nt2 {2w,2w+1}
  const int nt2b = w*2;
  float bn2v[2];
  #pragma unroll
  for (int i=0;i<2;++i) bn2v[i] = bn2[(nt2b+i)*16 + l15];
  f4v acc2[4][2];
  #pragma unroll
  for (int mt=0;mt<4;++mt)
    #pragma unroll
    for (int i=0;i<2;++i) acc2[mt][i] = splat4(bn2v[i]);
  #pragma unroll
  for (int kb = 0; kb < 4; ++kb){
    bf8v a2f[4];
    #pragma unroll
    for (int mt=0;mt<4;++mt){
      int row = l15 + 16*mt;
      int off = row*256 + ((kb*64 + lhi*16) ^ ((row&7)<<4));
      a2f[mt] = *reinterpret_cast<const bf8v*>((const char*)A2 + off);
    }
    #pragma unroll
    for (int i=0;i<2;++i){
      bf8v b2f = *reinterpret_cast<const bf8v*>(wn2f + (((kb*8 + nt2b+i)*64 + lane)<<3));
      #pragma unroll
      for (int mt=0;mt<4;++mt) acc2[mt][i] = mfma16(a2f[mt], b2f, acc2[mt][i]);
    }
  }
  __syncthreads();  // gate_arr ready

  // phase D (R4-proven): block-local softmax partials (exact flash combine)
  float g = gate_arr[lane];
  float M = g;
  #pragma unroll
  for (int d=1; d<64; d<<=1) M = fmaxf(M, __shfl_xor(M, d));
  float e = ex2((g - M)*L2E);
  float sE = e;
  #pragma unroll
  for (int d=1; d<64; d<<=1) sE += __shfl_xor(sE, d);
  float ev0 = 0.f, ev1 = 0.f;
  #pragma unroll
  for (int mt=0;mt<4;++mt)
    #pragma unroll
    for (int r=0;r<4;++r){
      int row = mt*16 + lhi*4 + r;
      float wm = ex2((gate_arr[row] - M)*L2E);
      ev0 += wm*acc2[mt][0][r];
      ev1 += wm*acc2[mt][1][r];
    }
  ev0 += __shfl_xor(ev0, 16); ev0 += __shfl_xor(ev0, 32);
  ev1 += __shfl_xor(ev1, 16); ev1 += __shfl_xor(ev1, 32);

  float* pb = partials + (size_t)seq*130;
  if (tid == 0){ pb[0] = M; pb[1] = sE; }
  if (lane < 16){
    pb[2 + (nt2b+0)*16 + lane] = ev0;
    pb[2 + (nt2b+1)*16 + lane] = ev1;
  }
}

// ---------- combine: merge 64 partials per batch ----------
__global__ void combine_kernel(const float* __restrict__ partials, float* __restrict__ out)
{
  int b = blockIdx.x; int j = threadIdx.x;  // 128 threads
  const float* pb = partials + (size_t)b*64*130;
  float M = -3.0e38f;
  for (int p = 0; p < 64; ++p) M = fmaxf(M, pb[p*130]);
  float num = 0.f, den = 0.f;
  for (int p = 0; p < 64; ++p){
    float wm = ex2((pb[p*130] - M)*L2E);
    den += wm * pb[p*130 + 1];
    num += wm * pb[p*130 + 2 + j];
  }
  out[b*128 + j] = num / den;
}

// ---------- host ----------
extern "C" void kernel_launch(void* const* d_in, const int* in_sizes, int n_in,
                              void* d_out, int out_size, void* d_ws, size_t ws_size,
                              hipStream_t stream) {
  (void)in_sizes; (void)n_in; (void)out_size; (void)ws_size;
  const float* x     = (const float*)d_in[0];
  const float* W_emb = (const float*)d_in[1];
  const float* b_emb = (const float*)d_in[2];
  const float* W_ih  = (const float*)d_in[3];
  const float* W_hh  = (const float*)d_in[4];
  const float* b_ih  = (const float*)d_in[5];
  const float* b_hh  = (const float*)d_in[6];
  const float* Wg1   = (const float*)d_in[7];
  const float* bg1   = (const float*)d_in[8];
  const float* Wg2   = (const float*)d_in[9];
  const float* bg2   = (const float*)d_in[10];
  const float* Wn1   = (const float*)d_in[11];
  const float* bn1   = (const float*)d_in[12];
  const float* Wn2   = (const float*)d_in[13];
  const float* bn2   = (const float*)d_in[14];

  char* p = (char*)d_ws;
  short* bhhf    = (short*)p; p += 98304;
  short* wcxf    = (short*)p; p += 16384;
  short* wchf    = (short*)p; p += 65536;
  short* wn2f    = (short*)p; p += 32768;
  short* w2f     = (short*)p; p += 24576;
  float* b2      = (float*)p; p += 1536;
  short* xfrag   = (short*)p; p += 8388608;
  short* xf2     = (short*)p; p += 8388608;
  short* svb     = (short*)p; p += 4194304;
  float* rbf     = (float*)p; p += 65536;
  float* partials = (float*)p; p += (size_t)8192*130*4;

  prep_kernel<<<2578, 256, 0, stream>>>(x, W_emb, b_emb, W_ih, W_hh, b_ih,
                                        Wg1, Wn1, Wn2, bg1, bn1,
                                        bhhf, wcxf, wchf, wn2f, w2f, b2,
                                        xfrag, xf2, rbf);
  gru_kernel<<<512, 512, 0, stream>>>(xfrag, bhhf, w2f, b2, b_hh, wchf, svb);
  feats_kernel<<<8192, 256, 0, stream>>>(xf2, svb, rbf, wcxf, wn2f,
                                         Wg2, bg2, bn2, partials);
  combine_kernel<<<128, 128, 0, stream>>>(partials, (float*)d_out);
}